// Round 12
// baseline (238.726 us; speedup 1.0000x reference)
//
#include <hip/hip_runtime.h>
#include <hip/hip_bf16.h>
#include <math.h>

// Problem constants
#define LSEQ   4096
#define DIM    768
#define DINNER 1536
#define DSTATE 16
#define NCOLS  4640          // 3*DINNER + 2*DSTATE
#define NCH    256           // scan chunks
#define CLEN   16            // steps per chunk
#define NPAD   4736          // W_in rows padded to 37*128
#define DXW    1568          // compact f32 width: B(16) C(16) delta(1536)

typedef _Float16 f16;
typedef __attribute__((ext_vector_type(2))) _Float16 f16x2;
typedef __attribute__((ext_vector_type(4))) _Float16 f16x4;
typedef __attribute__((ext_vector_type(8))) _Float16 f16x8;
typedef __attribute__((ext_vector_type(4))) float f32x4;

// async global(16B/lane) -> LDS staging
__device__ __forceinline__ void gld_lds16(void* lds_dst, const void* gsrc) {
    __builtin_amdgcn_global_load_lds(
        (__attribute__((address_space(1))) void*)(gsrc),
        (__attribute__((address_space(3))) void*)(lds_dst), 16, 0, 0);
}

// ---------------------------------------------------------------------------
// GEMM1: C = A[4096,768](f16) * B[4736,768]^T(f16). r2 schedule; r8 mapping.
//   BM=256 x BN=128, BK=64, 8 waves (512 thr), per-wave 64x64 (waves 4M x 2N).
//   3-deep cyclic LDS ring (144KB), prefetch distance 2, counted vmcnt(6),
//   4-phase quadrant schedule per K-tile (P00/P01/P10 with ds_read+stage,
//   P11 register-only), sched_barrier(0) after inline lgkmcnt(0) (rule #18).
//   8Mx37N supertile mapping: FETCH 72.7 -> 45.6 MB measured (r8).
//   LDS swizzle (verified conflict-free): global 16B block b of row r ->
//   LDS block b^(r&7); frag read fo=((q+4kk)^(m&7))<<3.
//   Epilogue: n0<1536 -> f16 Xb, <3072 -> f16 Zb, else f32 C (ldc=DXW).
// ---------------------------------------------------------------------------
#define G1K    768
#define G1_NT  12            // K-tiles of 64
#define G1_BM  256
#define G1_BN  128
#define G1_RT  384           // rows per K-tile (BM+BN)
#define G1_LDSE (G1_RT * 64) // f16 elems per ring slot (48KB)

__global__ __launch_bounds__(512) void gemm1_pipe(const f16* __restrict__ A,
                                                  const f16* __restrict__ B,
                                                  float* __restrict__ C,
                                                  f16* __restrict__ Xb,
                                                  f16* __restrict__ Zb) {
    __shared__ __align__(16) f16 S[3 * G1_LDSE];   // 144 KB ring

    const int P   = gridDim.x >> 3;                // XCD swizzle: 592 = 8*74
    const int idx = (blockIdx.x & 7) * P + (blockIdx.x >> 3);
    const int sm  = idx / 296;                     // supertile: 8 M-tiles x 37 N
    const int rem = idx - sm * 296;
    const int m0  = (sm * 8 + (rem & 7)) * G1_BM;  // 16 M-tiles total
    const int n0  = (rem >> 3) * G1_BN;            // 37 N-tiles

    const int tid  = threadIdx.x;
    const int w    = tid >> 6;                     // wave 0..7
    const int lane = tid & 63;
    const int wr   = w >> 1;                       // 0..3 (M)
    const int wc   = w & 1;                        // 0..1 (N)
    const int m    = lane & 15;                    // fragment row(A)/col(B)
    const int q    = lane >> 4;                    // quad
    const int rl8  = lane >> 3;                    // staging: row in 8-row group
    const int bsel = lane & 7;                     // staging: 16B-block index

    // staging map: 48 x 1KB instrs per K-tile; wave w takes t = w + 8*s.
    const f16* gb[6];
#pragma unroll
    for (int s = 0; s < 6; ++s) {
        const int rl  = (w + 8 * s) * 8 + rl8;
        const int blk = bsel ^ (rl & 7);
        gb[s] = (rl < G1_BM) ? A + (size_t)(m0 + rl) * G1K + blk * 8
                             : B + (size_t)(n0 + rl - G1_BM) * G1K + blk * 8;
    }

    f32x4 acc[4][4];
#pragma unroll
    for (int i = 0; i < 4; i++)
#pragma unroll
        for (int j = 0; j < 4; j++) acc[i][j] = (f32x4){0.f, 0.f, 0.f, 0.f};

    auto stg2 = [&](int kt, int s0) {  // issue 2 of K-tile kt's 6 staging instrs
        f16* dst = S + (kt % 3) * G1_LDSE;
#pragma unroll
        for (int s = s0; s < s0 + 2; ++s)
            gld_lds16(dst + (w + 8 * s) * 512, gb[s] + kt * 64);
    };
    auto stg6 = [&](int kt) {
        f16* dst = S + (kt % 3) * G1_LDSE;
#pragma unroll
        for (int s = 0; s < 6; ++s)
            gld_lds16(dst + (w + 8 * s) * 512, gb[s] + kt * 64);
    };

    // prologue: tiles 0 and 1 in flight (12 outstanding/wave)
    stg6(0);
    stg6(1);

#pragma unroll
    for (int kt = 0; kt < G1_NT; ++kt) {
        // drain tile kt's 6 loads (oldest); tile kt+1's 6 stay in flight.
        if (kt < G1_NT - 1) asm volatile("s_waitcnt vmcnt(6)" ::: "memory");
        else                asm volatile("s_waitcnt vmcnt(0)" ::: "memory");
        __builtin_amdgcn_s_barrier();   // all waves' stg(kt) landed; slot
                                        // (kt-1)%3's readers are all past.
        const f16* As = S + (kt % 3) * G1_LDSE;
        const f16* Bs = As + G1_BM * 64;
        const bool pf = (kt + 2 < G1_NT);

        f16x8 af0[2][2], af2[2][2], bh0[2][2], bh2[2][2]; // [kk][half-idx]

        // ---- P00: read af01 + bh01 (8), stage 2, MFMA quadrant (i01 x j01)
#pragma unroll
        for (int kk = 0; kk < 2; ++kk) {
            const int fo = (((q + 4 * kk) ^ (m & 7)) << 3);
#pragma unroll
            for (int i = 0; i < 2; ++i) {
                af0[kk][i] = *(const f16x8*)&As[(wr * 64 + i * 16 + m) * 64 + fo];
                bh0[kk][i] = *(const f16x8*)&Bs[(wc * 64 + i * 16 + m) * 64 + fo];
            }
        }
        if (pf) stg2(kt + 2, 0);
        __builtin_amdgcn_s_barrier();
        asm volatile("s_waitcnt lgkmcnt(0)" ::: "memory");
        __builtin_amdgcn_sched_barrier(0);
        __builtin_amdgcn_s_setprio(1);
#pragma unroll
        for (int kk = 0; kk < 2; ++kk)
#pragma unroll
            for (int i = 0; i < 2; ++i)
#pragma unroll
                for (int j = 0; j < 2; ++j)
                    acc[i][j] = __builtin_amdgcn_mfma_f32_16x16x32_f16(
                        af0[kk][i], bh0[kk][j], acc[i][j], 0, 0, 0);
        __builtin_amdgcn_s_setprio(0);

        // ---- P01: read bh23 (4), stage 2, MFMA quadrant (i01 x j23)
#pragma unroll
        for (int kk = 0; kk < 2; ++kk) {
            const int fo = (((q + 4 * kk) ^ (m & 7)) << 3);
#pragma unroll
            for (int j = 0; j < 2; ++j)
                bh2[kk][j] = *(const f16x8*)&Bs[(wc * 64 + (j + 2) * 16 + m) * 64 + fo];
        }
        if (pf) stg2(kt + 2, 2);
        __builtin_amdgcn_s_barrier();
        asm volatile("s_waitcnt lgkmcnt(0)" ::: "memory");
        __builtin_amdgcn_sched_barrier(0);
        __builtin_amdgcn_s_setprio(1);
#pragma unroll
        for (int kk = 0; kk < 2; ++kk)
#pragma unroll
            for (int i = 0; i < 2; ++i)
#pragma unroll
                for (int j = 0; j < 2; ++j)
                    acc[i][j + 2] = __builtin_amdgcn_mfma_f32_16x16x32_f16(
                        af0[kk][i], bh2[kk][j], acc[i][j + 2], 0, 0, 0);
        __builtin_amdgcn_s_setprio(0);

        // ---- P10: read af23 (4), stage 2, MFMA quadrant (i23 x j01)
#pragma unroll
        for (int kk = 0; kk < 2; ++kk) {
            const int fo = (((q + 4 * kk) ^ (m & 7)) << 3);
#pragma unroll
            for (int i = 0; i < 2; ++i)
                af2[kk][i] = *(const f16x8*)&As[(wr * 64 + (i + 2) * 16 + m) * 64 + fo];
        }
        if (pf) stg2(kt + 2, 4);
        __builtin_amdgcn_s_barrier();
        asm volatile("s_waitcnt lgkmcnt(0)" ::: "memory");
        __builtin_amdgcn_sched_barrier(0);
        __builtin_amdgcn_s_setprio(1);
#pragma unroll
        for (int kk = 0; kk < 2; ++kk)
#pragma unroll
            for (int i = 0; i < 2; ++i)
#pragma unroll
                for (int j = 0; j < 2; ++j)
                    acc[i + 2][j] = __builtin_amdgcn_mfma_f32_16x16x32_f16(
                        af2[kk][i], bh0[kk][j], acc[i + 2][j], 0, 0, 0);
        __builtin_amdgcn_s_setprio(0);

        // ---- P11: register-only MFMA quadrant (i23 x j23), no barrier needed
        __builtin_amdgcn_s_setprio(1);
#pragma unroll
        for (int kk = 0; kk < 2; ++kk)
#pragma unroll
            for (int i = 0; i < 2; ++i)
#pragma unroll
                for (int j = 0; j < 2; ++j)
                    acc[i + 2][j + 2] = __builtin_amdgcn_mfma_f32_16x16x32_f16(
                        af2[kk][i], bh2[kk][j], acc[i + 2][j + 2], 0, 0, 0);
        __builtin_amdgcn_s_setprio(0);
    }

    // epilogue: C/D layout col=lane&15, row=q*4+reg
    if (n0 < DINNER) {                     // x_inner cols -> f16 Xb
#pragma unroll
        for (int i = 0; i < 4; i++)
#pragma unroll
            for (int j = 0; j < 4; j++) {
                const int col  = n0 + wc * 64 + j * 16 + m;
                const int rowb = m0 + wr * 64 + i * 16 + q * 4;
#pragma unroll
                for (int r = 0; r < 4; r++)
                    Xb[(size_t)(rowb + r) * DINNER + col] = (f16)acc[i][j][r];
            }
        return;
    }
    if (n0 < 2 * DINNER) {                 // z cols -> f16 Zb
#pragma unroll
        for (int i = 0; i < 4; i++)
#pragma unroll
            for (int j = 0; j < 4; j++) {
                const int col  = n0 - DINNER + wc * 64 + j * 16 + m;
                const int rowb = m0 + wr * 64 + i * 16 + q * 4;
#pragma unroll
                for (int r = 0; r < 4; r++)
                    Zb[(size_t)(rowb + r) * DINNER + col] = (f16)acc[i][j][r];
            }
        return;
    }
#pragma unroll
    for (int i = 0; i < 4; i++)            // B|C|delta -> f32 C at ldc=DXW
#pragma unroll
        for (int j = 0; j < 4; j++) {
            const int col = n0 - 2 * DINNER + wc * 64 + j * 16 + m;
            if (col >= DXW) continue;
            const int rowb = m0 + wr * 64 + i * 16 + q * 4;
#pragma unroll
            for (int r = 0; r < 4; r++)
                C[(size_t)(rowb + r) * DXW + col] = acc[i][j][r];
        }
}

// ---------------------------------------------------------------------------
// GEMM2 (r7 winner): out = Ay[4096,1536](f16) * Bo[768,1536]^T(f16).
//   BM=BN=64, BK=64, 4 waves, ring of 3 x 16KB, counted vmcnt(4), 24 K-tiles.
// ---------------------------------------------------------------------------
#define G2K    1536
#define G2_NT  24            // K-tiles of 64
#define G2_LDSE (128 * 64)   // f16 elems per ring slot (16KB)

__global__ __launch_bounds__(256) void gemm2_pipe(const f16* __restrict__ A,
                                                  const f16* __restrict__ B,
                                                  float* __restrict__ C) {
    __shared__ __align__(16) f16 S[3 * G2_LDSE];   // 48 KB ring

    const int P   = gridDim.x >> 3;                // XCD swizzle: 768 = 8*96
    const int idx = (blockIdx.x & 7) * P + (blockIdx.x >> 3);
    const int m0  = (idx / 12) * 64;               // 64 M-tiles (A-locality slab)
    const int n0  = (idx % 12) * 64;               // 12 N-tiles

    const int tid  = threadIdx.x;
    const int w    = tid >> 6;                     // wave 0..3
    const int lane = tid & 63;
    const int wr   = w >> 1;                       // 0..1 (M)
    const int wc   = w & 1;                        // 0..1 (N)
    const int m    = lane & 15;
    const int q    = lane >> 4;
    const int rl8  = lane >> 3;
    const int bsel = lane & 7;

    // staging map: 16 x 1KB instrs per K-tile; wave w takes t = w + 4*s.
    const f16* gb[4];
#pragma unroll
    for (int s = 0; s < 4; ++s) {
        const int rl  = (w + 4 * s) * 8 + rl8;
        const int blk = bsel ^ (rl & 7);
        gb[s] = (rl < 64) ? A + (size_t)(m0 + rl) * G2K + blk * 8
                          : B + (size_t)(n0 + rl - 64) * G2K + blk * 8;
    }

    f32x4 acc[2][2];
#pragma unroll
    for (int i = 0; i < 2; i++)
#pragma unroll
        for (int j = 0; j < 2; j++) acc[i][j] = (f32x4){0.f, 0.f, 0.f, 0.f};

    auto stg = [&](int kt) {
        f16* dst = S + (kt % 3) * G2_LDSE;
#pragma unroll
        for (int s = 0; s < 4; ++s)
            gld_lds16(dst + (w + 4 * s) * 512, gb[s] + kt * 64);
    };

    stg(0);
    stg(1);

#pragma unroll
    for (int kt = 0; kt < G2_NT; ++kt) {
        // drain tile kt's 4 loads (oldest); tile kt+1's 4 stay in flight.
        if (kt < G2_NT - 1) asm volatile("s_waitcnt vmcnt(4)" ::: "memory");
        else                asm volatile("s_waitcnt vmcnt(0)" ::: "memory");
        __builtin_amdgcn_s_barrier();   // tile kt fully staged; slot (kt-1)%3's
                                        // readers (tile kt-1, pre-barrier) done.
        if (kt + 2 < G2_NT) stg(kt + 2);

        const f16* As = S + (kt % 3) * G2_LDSE;
        const f16* Bs = As + 64 * 64;

        f16x8 af[2][2], bh[2][2];      // [kk][tile]
#pragma unroll
        for (int kk = 0; kk < 2; ++kk) {
            const int fo = (((q + 4 * kk) ^ (m & 7)) << 3);
#pragma unroll
            for (int i = 0; i < 2; ++i) {
                af[kk][i] = *(const f16x8*)&As[(wr * 32 + i * 16 + m) * 64 + fo];
                bh[kk][i] = *(const f16x8*)&Bs[(wc * 32 + i * 16 + m) * 64 + fo];
            }
        }
        asm volatile("s_waitcnt lgkmcnt(0)" ::: "memory");
        __builtin_amdgcn_sched_barrier(0);
        __builtin_amdgcn_s_setprio(1);
#pragma unroll
        for (int kk = 0; kk < 2; ++kk)
#pragma unroll
            for (int i = 0; i < 2; ++i)
#pragma unroll
                for (int j = 0; j < 2; ++j)
                    acc[i][j] = __builtin_amdgcn_mfma_f32_16x16x32_f16(
                        af[kk][i], bh[kk][j], acc[i][j], 0, 0, 0);
        __builtin_amdgcn_s_setprio(0);
    }

    // epilogue: C/D layout col=lane&15, row=q*4+reg
#pragma unroll
    for (int i = 0; i < 2; i++)
#pragma unroll
        for (int j = 0; j < 2; j++) {
            const int col  = n0 + wc * 32 + j * 16 + m;
            const int rowb = m0 + wr * 32 + i * 16 + q * 4;
#pragma unroll
            for (int r = 0; r < 4; r++)
                C[(size_t)(rowb + r) * DIM + col] = acc[i][j][r];
        }
}

// ---------------------------------------------------------------------------
// merged conversions: Ax (f16 x), Bw (f16 W_in, zero-padded), Bo (f16 W_out).
// Packed f16x4 (8B) stores.
// ---------------------------------------------------------------------------
#define E0 (LSEQ * DIM)            // 3,145,728
#define E1 (E0 + NPAD * DIM)       // + 3,637,248
#define E2 (E1 + DIM * DINNER)     // + 1,179,648

__global__ __launch_bounds__(256) void cvt_all(const float* __restrict__ x,
                                               const float* __restrict__ Wi,
                                               const float* __restrict__ Wo,
                                               f16* __restrict__ Ax,
                                               f16* __restrict__ Bw,
                                               f16* __restrict__ Bo) {
    int i = (blockIdx.x * 256 + threadIdx.x) * 4;
    if (i < E0) {
        float4 v = *(const float4*)(x + i);
        f16x4 o = {(f16)v.x, (f16)v.y, (f16)v.z, (f16)v.w};
        *(f16x4*)(Ax + i) = o;
    } else if (i < E1) {
        int e = i - E0;
        int n = e / DIM;
        if (n < NCOLS) {
            float4 v = *(const float4*)(Wi + e);
            f16x4 o = {(f16)v.x, (f16)v.y, (f16)v.z, (f16)v.w};
            *(f16x4*)(Bw + e) = o;
        } else {
            f16x4 o = {(f16)0.f, (f16)0.f, (f16)0.f, (f16)0.f};
            *(f16x4*)(Bw + e) = o;
        }
    } else if (i < E2) {
        int e = i - E1;
        float4 v = *(const float4*)(Wo + e);
        f16x4 o = {(f16)v.x, (f16)v.y, (f16)v.z, (f16)v.w};
        *(f16x4*)(Bo + e) = o;
    }
}

// ---------------------------------------------------------------------------
// scan phase 1 (r12: + y1/Scum emission): conv+silu+softplus fused; local
// scan h=0 -> h_end; store S, hend, AND per-step y1 = C_t.h_local_t (f32,
// -> Y1 buffer) + Scum_t (running sum of dtv, stored IN-PLACE into Dxz's
// delta columns — this block staged them to LDS already; partitions are
// disjoint; gemm1 rewrites delta each iteration -> re-poison safe).
// Linearity: h_t = exp(Scum_t*Ar) (.) h_init + h_local_t, so scan3 needs
// only (y1, Scum, hinit) and has NO serial chain (see scan3_kernel).
// LDS bulk-staged x/delta (r10); 2 ch/thread.
// ---------------------------------------------------------------------------
__global__ __launch_bounds__(256, 3) void scan1_kernel(float* __restrict__ Dxz,
                                                       const f16* __restrict__ Xb,
                                                       const float* __restrict__ Wc,
                                                       const float* __restrict__ A_log,
                                                       float* __restrict__ Sb,
                                                       float* __restrict__ hend,
                                                       float* __restrict__ Y1) {
    __shared__ __align__(16) f16   Xs[18 * 512];   // rows l0-1 .. l0+16 (18KB)
    __shared__ __align__(16) float Ds[16 * 512];   // delta rows (32KB)
    __shared__ float Bs[CLEN * DSTATE];            // 1KB
    __shared__ float Cs[CLEN * DSTATE];            // 1KB
    const int tid  = threadIdx.x;
    const int w4   = tid >> 6;
    const int lane = tid & 63;
    const int ch0  = blockIdx.x * 512;             // block channel base
    const int d0   = ch0 + 2 * tid;
    const int c    = blockIdx.y;
    const int l0   = c * CLEN;

    // stage x rows r=0..17 (global row l0-1+r); skip out-of-range rows
    for (int r = w4; r < 18; r += 4) {
        const int gr = l0 - 1 + r;
        if (gr >= 0 && gr < LSEQ)
            gld_lds16(Xs + r * 512, Xb + (size_t)gr * DINNER + ch0 + lane * 8);
    }
    // stage delta rows t=0..15, two 1KB halves each (32 instrs)
    for (int i = w4; i < 32; i += 4) {
        const int t = i >> 1, hh = i & 1;
        gld_lds16(Ds + t * 512 + hh * 256,
                  Dxz + (size_t)(l0 + t) * DXW + 32 + ch0 + hh * 256 + lane * 4);
    }
    for (int i = tid; i < CLEN * DSTATE; i += 256) {
        size_t roff = (size_t)(l0 + (i >> 4)) * DXW;
        Bs[i] = Dxz[roff + (i & 15)];
        Cs[i] = Dxz[roff + 16 + (i & 15)];
    }

    float Ar0[DSTATE], Ar1[DSTATE];
#pragma unroll
    for (int n = 0; n < DSTATE; n++) {
        Ar0[n] = -__expf(A_log[d0 * DSTATE + n]);
        Ar1[n] = -__expf(A_log[(d0 + 1) * DSTATE + n]);
    }
    const float w00 = Wc[d0 * 3 + 0], w01 = Wc[d0 * 3 + 1], w02 = Wc[d0 * 3 + 2];
    const float w10 = Wc[d0 * 3 + 3], w11 = Wc[d0 * 3 + 4], w12 = Wc[d0 * 3 + 5];

    asm volatile("s_waitcnt vmcnt(0)" ::: "memory");   // all staging landed
    // zero-fill edge rows that were never staged
    if (l0 == 0)
        *(f16x2*)&Xs[2 * tid] = (f16x2){(f16)0.f, (f16)0.f};
    if (c == NCH - 1)
        *(f16x2*)&Xs[17 * 512 + 2 * tid] = (f16x2){(f16)0.f, (f16)0.f};
    __syncthreads();

    auto ldx = [&](int r) -> float2 {
        f16x2 v = *(const f16x2*)&Xs[r * 512 + 2 * tid];
        return make_float2((float)v.x, (float)v.y);
    };

    float h0[DSTATE], h1[DSTATE];
#pragma unroll
    for (int n = 0; n < DSTATE; n++) { h0[n] = 0.f; h1[n] = 0.f; }
    float S0 = 0.f, S1 = 0.f;

    float2 xm = ldx(0);
    float2 x0 = ldx(1);
    for (int t = 0; t < CLEN; t++) {
        const int l = l0 + t;
        float2 xp = ldx(t + 2);
        float2 dr = *(const float2*)&Ds[t * 512 + 2 * tid];
        float v0  = xm.x * w00 + x0.x * w01 + xp.x * w02;
        float v1  = xm.y * w10 + x0.y * w11 + xp.y * w12;
        float xc0 = __fdividef(v0, 1.f + __expf(-v0));
        float xc1 = __fdividef(v1, 1.f + __expf(-v1));
        float dt0 = (dr.x > 20.f) ? dr.x : __logf(1.f + __expf(dr.x));
        float dt1 = (dr.y > 20.f) ? dr.y : __logf(1.f + __expf(dr.y));
        float u0 = dt0 * xc0, u1 = dt1 * xc1;
        S0 += dt0; S1 += dt1;
        float y0 = 0.f, y1a = 0.f;
#pragma unroll
        for (int n = 0; n < DSTATE; n++) {
            float b  = Bs[t * DSTATE + n];
            float cc = Cs[t * DSTATE + n];
            h0[n] = __expf(dt0 * Ar0[n]) * h0[n] + u0 * b;
            h1[n] = __expf(dt1 * Ar1[n]) * h1[n] + u1 * b;
            y0  += h0[n] * cc;
            y1a += h1[n] * cc;
        }
        // per-step emissions for the linearized scan3
        *(float2*)&Dxz[(size_t)l * DXW + 32 + d0] = make_float2(S0, S1);  // Scum
        *(float2*)&Y1[(size_t)l * DINNER + d0]    = make_float2(y0, y1a);
        xm = x0; x0 = xp;
    }
    *(float2*)&Sb[(size_t)c * DINNER + d0] = make_float2(S0, S1);
#pragma unroll
    for (int n = 0; n < DSTATE; n++)
        *(float2*)&hend[((size_t)c * DSTATE + n) * DINNER + d0] = make_float2(h0[n], h1[n]);
}

// ---------------------------------------------------------------------------
// scan phase 2 (r11 hierarchical + r12 in-place): 16 groups x 16 chunks;
// group affine compose -> LDS scan -> replay. hinit is written IN-PLACE over
// hend (each thread loads all its hend values before writing; columns are
// thread-exclusive -> race-free). Frees 25MB for the Y1 buffer.
// ---------------------------------------------------------------------------
__global__ __launch_bounds__(256) void scan2_kernel(const float* __restrict__ Sb,
                                                    const float* __restrict__ A_log,
                                                    float* __restrict__ h_io) {
    __shared__ float As_[16][17];   // [group][elem] (+1 pad)
    __shared__ float Es_[16][17];
    __shared__ float Hs_[16][17];   // group-start h
    const int tid = threadIdx.x;
    const int el  = tid & 15;                 // element within block
    const int grp = tid >> 4;                 // group 0..15
    const int g   = blockIdx.x * 16 + el;     // global element = n*DINNER+d
    const int n   = g / DINNER;
    const int d   = g - n * DINNER;
    const float Ar = -__expf(A_log[d * DSTATE + n]);
    const size_t S = (size_t)DSTATE * DINNER;

    // batch-load this group's 16 (s,e) pairs — 32 independent loads
    float sv[16], ev[16];
#pragma unroll
    for (int k = 0; k < 16; ++k) {
        const int c = grp * 16 + k;
        sv[k] = Sb[(size_t)c * DINNER + d];
        ev[k] = h_io[(size_t)c * S + g];
    }
    // compose group affine (A,E); keep a_k for the replay
    float av[16];
    float A = 1.f, E = 0.f;
#pragma unroll
    for (int k = 0; k < 16; ++k) {
        av[k] = __expf(sv[k] * Ar);
        E = av[k] * E + ev[k];
        A = av[k] * A;
    }
    As_[grp][el] = A;
    Es_[grp][el] = E;
    __syncthreads();
    if (tid < 16) {                           // per-elem scan over 16 groups
        float h = 0.f;
#pragma unroll
        for (int gq = 0; gq < 16; ++gq) {
            Hs_[gq][tid] = h;
            h = As_[gq][tid] * h + Es_[gq][tid];
        }
    }
    __syncthreads();
    // replay: hinit for each chunk in this thread's group (in-place over hend)
    float h = Hs_[grp][el];
#pragma unroll
    for (int k = 0; k < 16; ++k) {
        const int c = grp * 16 + k;
        h_io[(size_t)c * S + g] = h;
        h = av[k] * h + ev[k];
    }
}

// ---------------------------------------------------------------------------
// scan phase 3 (r12: LINEARIZED — no serial chain): per (l,d) independent:
//   y = y1[l,d] + SUM_n C_t[n] * exp(Scum[l,d]*Ar[n]) * hinit[chunk][n][d]
//   out = (y + xcv*Dv) * silu(z),  xcv recomputed bit-identically from Xb.
// hinit held in 32 registers (loaded once per thread, fixed chunk); only Cs
// in LDS (1KB) -> high occupancy; 16 t-iterations fully independent -> deep
// ILP, all loads pipelined. exp(Scum*Ar) <= 1 (Scum>=0, Ar<0): no overflow.
// ---------------------------------------------------------------------------
__global__ __launch_bounds__(256) void scan3_kernel(const float* __restrict__ Dxz,
                                                    const f16* __restrict__ Xb,
                                                    const f16* __restrict__ Zb,
                                                    const float* __restrict__ Wc,
                                                    const float* __restrict__ A_log,
                                                    const float* __restrict__ hin,
                                                    const float* __restrict__ Y1,
                                                    const float* __restrict__ Dp,
                                                    f16* __restrict__ Ay) {
    __shared__ float Cs[CLEN * DSTATE];            // 1KB
    const int tid = threadIdx.x;
    const int d0  = (blockIdx.x * 256 + tid) * 2;
    const int c   = blockIdx.y;
    const int l0  = c * CLEN;
    for (int i = tid; i < CLEN * DSTATE; i += 256)
        Cs[i] = Dxz[(size_t)(l0 + (i >> 4)) * DXW + 16 + (i & 15)];

    float Ar0[DSTATE], Ar1[DSTATE];
#pragma unroll
    for (int n = 0; n < DSTATE; n++) {
        Ar0[n] = -__expf(A_log[d0 * DSTATE + n]);
        Ar1[n] = -__expf(A_log[(d0 + 1) * DSTATE + n]);
    }
    float hin0[DSTATE], hin1[DSTATE];
#pragma unroll
    for (int n = 0; n < DSTATE; n++) {
        float2 hv = *(const float2*)&hin[((size_t)c * DSTATE + n) * DINNER + d0];
        hin0[n] = hv.x; hin1[n] = hv.y;
    }
    const float Dv0 = Dp[d0], Dv1 = Dp[d0 + 1];
    const float w00 = Wc[d0 * 3 + 0], w01 = Wc[d0 * 3 + 1], w02 = Wc[d0 * 3 + 2];
    const float w10 = Wc[d0 * 3 + 3], w11 = Wc[d0 * 3 + 4], w12 = Wc[d0 * 3 + 5];

    auto ldx2 = [&](int l) -> float2 {
        f16x2 v = *(const f16x2*)&Xb[(size_t)l * DINNER + d0];
        return make_float2((float)v.x, (float)v.y);
    };
    auto ldz2 = [&](int l) -> float2 {
        f16x2 v = *(const f16x2*)&Zb[(size_t)l * DINNER + d0];
        return make_float2((float)v.x, (float)v.y);
    };
    float2 xm = (l0 > 0) ? ldx2(l0 - 1) : make_float2(0.f, 0.f);
    float2 x0 = ldx2(l0);
    __syncthreads();

#pragma unroll 4
    for (int t = 0; t < CLEN; t++) {
        const int l = l0 + t;
        float2 xp = (l + 1 < LSEQ) ? ldx2(l + 1) : make_float2(0.f, 0.f);
        float2 zv = ldz2(l);
        float2 sc = *(const float2*)&Dxz[(size_t)l * DXW + 32 + d0];  // Scum
        float2 yv = *(const float2*)&Y1[(size_t)l * DINNER + d0];
        float v0  = xm.x * w00 + x0.x * w01 + xp.x * w02;
        float v1  = xm.y * w10 + x0.y * w11 + xp.y * w12;
        float xc0 = __fdividef(v0, 1.f + __expf(-v0));
        float xc1 = __fdividef(v1, 1.f + __expf(-v1));
        float y0 = yv.x, y1a = yv.y;
#pragma unroll
        for (int n = 0; n < DSTATE; n++) {
            float cc = Cs[t * DSTATE + n];
            y0  += cc * __expf(sc.x * Ar0[n]) * hin0[n];
            y1a += cc * __expf(sc.y * Ar1[n]) * hin1[n];
        }
        float sz0 = __fdividef(zv.x, 1.f + __expf(-zv.x));
        float sz1 = __fdividef(zv.y, 1.f + __expf(-zv.y));
        f16x2 o = {(f16)((y0 + xc0 * Dv0) * sz0), (f16)((y1a + xc1 * Dv1) * sz1)};
        *(f16x2*)&Ay[(size_t)l * DINNER + d0] = o;
        xm = x0; x0 = xp;
    }
}

// ---------------------------------------------------------------------------
extern "C" void kernel_launch(void* const* d_in, const int* in_sizes, int n_in,
                              void* d_out, int out_size, void* d_ws, size_t ws_size,
                              hipStream_t stream) {
    const float* x     = (const float*)d_in[0];
    const float* W_in  = (const float*)d_in[1];
    const float* W_conv= (const float*)d_in[2];
    const float* W_out = (const float*)d_in[3];
    const float* A_log = (const float*)d_in[4];
    const float* Dp    = (const float*)d_in[5];
    float* out = (float*)d_out;

    // workspace carve-up (~111 MB; Y1 takes the old hinit slot — scan2 now
    // writes hinit in-place over hend)
    float* ws  = (float*)d_ws;
    float* Dxz = ws;                                  // 4096*1568 f32
    float* Y1  = Dxz + (size_t)LSEQ * DXW;            // y1: LSEQ*DINNER f32
    float* he  = Y1 + (size_t)LSEQ * DINNER;          // hend->hinit (in-place)
    float* Sb  = he + (size_t)NCH * DSTATE * DINNER;  // S: NCH*1536
    f16* Ax = (f16*)(Sb + (size_t)NCH * DINNER);      // 4096*768
    f16* Ay = Ax + (size_t)LSEQ * DIM;                // 4096*1536
    f16* Bw = Ay + (size_t)LSEQ * DINNER;             // 4736*768
    f16* Bo = Bw + (size_t)NPAD * DIM;                // 768*1536
    f16* Zb = Bo + (size_t)DIM * DINNER;              // 4096*1536
    f16* Xb = Zb + (size_t)LSEQ * DINNER;             // 4096*1536

    // 0) conversions (one kernel, f16x4 packed stores)
    cvt_all<<<E2 / 1024, 256, 0, stream>>>(x, W_in, W_out, Ax, Bw, Bo);

    // 1) xz = x @ W_in^T : 4-phase pipelined 256x128 tiles, counted vmcnt(6).
    //    592 blocks (= 8*74 XCD swizzle), 8Mx37N supertile mapping.
    gemm1_pipe<<<592, 512, 0, stream>>>(Ax, Bw, Dxz, Xb, Zb);

    // 2) chunked scan: NCH=256 chunks of CLEN=16; linearized scan3
    scan1_kernel<<<dim3(DINNER / 512, NCH), 256, 0, stream>>>(
        Dxz, Xb, W_conv, A_log, Sb, he, Y1);
    scan2_kernel<<<(DINNER * DSTATE) / 16, 256, 0, stream>>>(Sb, A_log, he);
    scan3_kernel<<<dim3(DINNER / 512, NCH), 256, 0, stream>>>(
        Dxz, Xb, Zb, W_conv, A_log, he, Y1, Dp, Ay);

    // 3) out = Ay @ W_out^T : pipelined ring-of-3, counted vmcnt(4), 24 K-tiles.
    //    64 M-tiles x 12 N-tiles = 768 blocks (= 8*96, XCD swizzle, A-locality)
    gemm2_pipe<<<768, 256, 0, stream>>>(Ay, Bo, out);
}

// Round 13
// 232.131 us; speedup vs baseline: 1.0284x; 1.0284x over previous
//
#include <hip/hip_runtime.h>
#include <hip/hip_bf16.h>
#include <math.h>

// Problem constants
#define LSEQ   4096
#define DIM    768
#define DINNER 1536
#define DSTATE 16
#define NCOLS  4640          // 3*DINNER + 2*DSTATE
#define NCH    256           // scan chunks
#define CLEN   16            // steps per chunk
#define NPAD   4736          // W_in rows padded to 37*128
#define DXW    1568          // compact f32 width: B(16) C(16) delta(1536)

typedef _Float16 f16;
typedef __attribute__((ext_vector_type(2))) _Float16 f16x2;
typedef __attribute__((ext_vector_type(4))) _Float16 f16x4;
typedef __attribute__((ext_vector_type(8))) _Float16 f16x8;
typedef __attribute__((ext_vector_type(4))) float f32x4;

// async global(16B/lane) -> LDS staging
__device__ __forceinline__ void gld_lds16(void* lds_dst, const void* gsrc) {
    __builtin_amdgcn_global_load_lds(
        (__attribute__((address_space(1))) void*)(gsrc),
        (__attribute__((address_space(3))) void*)(lds_dst), 16, 0, 0);
}

// ---------------------------------------------------------------------------
// GEMM1: C = A[4096,768](f16) * B[4736,768]^T(f16). r2 schedule; r8 mapping.
//   BM=256 x BN=128, BK=64, 8 waves (512 thr), per-wave 64x64 (waves 4M x 2N).
//   3-deep cyclic LDS ring (144KB), prefetch distance 2, counted vmcnt(6),
//   4-phase quadrant schedule per K-tile (P00/P01/P10 with ds_read+stage,
//   P11 register-only), sched_barrier(0) after inline lgkmcnt(0) (rule #18).
//   8Mx37N supertile mapping: FETCH 72.7 -> 45.6 MB measured (r8).
//   LDS swizzle (verified conflict-free): global 16B block b of row r ->
//   LDS block b^(r&7); frag read fo=((q+4kk)^(m&7))<<3.
//   Epilogue: n0<1536 -> f16 Xb, <3072 -> f16 Zb, else f32 C (ldc=DXW).
//   Converged: 4 schedule structures (r0-r3) all plateau at 47-50us @ K=768.
// ---------------------------------------------------------------------------
#define G1K    768
#define G1_NT  12            // K-tiles of 64
#define G1_BM  256
#define G1_BN  128
#define G1_RT  384           // rows per K-tile (BM+BN)
#define G1_LDSE (G1_RT * 64) // f16 elems per ring slot (48KB)

__global__ __launch_bounds__(512) void gemm1_pipe(const f16* __restrict__ A,
                                                  const f16* __restrict__ B,
                                                  float* __restrict__ C,
                                                  f16* __restrict__ Xb,
                                                  f16* __restrict__ Zb) {
    __shared__ __align__(16) f16 S[3 * G1_LDSE];   // 144 KB ring

    const int P   = gridDim.x >> 3;                // XCD swizzle: 592 = 8*74
    const int idx = (blockIdx.x & 7) * P + (blockIdx.x >> 3);
    const int sm  = idx / 296;                     // supertile: 8 M-tiles x 37 N
    const int rem = idx - sm * 296;
    const int m0  = (sm * 8 + (rem & 7)) * G1_BM;  // 16 M-tiles total
    const int n0  = (rem >> 3) * G1_BN;            // 37 N-tiles

    const int tid  = threadIdx.x;
    const int w    = tid >> 6;                     // wave 0..7
    const int lane = tid & 63;
    const int wr   = w >> 1;                       // 0..3 (M)
    const int wc   = w & 1;                        // 0..1 (N)
    const int m    = lane & 15;                    // fragment row(A)/col(B)
    const int q    = lane >> 4;                    // quad
    const int rl8  = lane >> 3;                    // staging: row in 8-row group
    const int bsel = lane & 7;                     // staging: 16B-block index

    // staging map: 48 x 1KB instrs per K-tile; wave w takes t = w + 8*s.
    const f16* gb[6];
#pragma unroll
    for (int s = 0; s < 6; ++s) {
        const int rl  = (w + 8 * s) * 8 + rl8;
        const int blk = bsel ^ (rl & 7);
        gb[s] = (rl < G1_BM) ? A + (size_t)(m0 + rl) * G1K + blk * 8
                             : B + (size_t)(n0 + rl - G1_BM) * G1K + blk * 8;
    }

    f32x4 acc[4][4];
#pragma unroll
    for (int i = 0; i < 4; i++)
#pragma unroll
        for (int j = 0; j < 4; j++) acc[i][j] = (f32x4){0.f, 0.f, 0.f, 0.f};

    auto stg2 = [&](int kt, int s0) {  // issue 2 of K-tile kt's 6 staging instrs
        f16* dst = S + (kt % 3) * G1_LDSE;
#pragma unroll
        for (int s = s0; s < s0 + 2; ++s)
            gld_lds16(dst + (w + 8 * s) * 512, gb[s] + kt * 64);
    };
    auto stg6 = [&](int kt) {
        f16* dst = S + (kt % 3) * G1_LDSE;
#pragma unroll
        for (int s = 0; s < 6; ++s)
            gld_lds16(dst + (w + 8 * s) * 512, gb[s] + kt * 64);
    };

    // prologue: tiles 0 and 1 in flight (12 outstanding/wave)
    stg6(0);
    stg6(1);

#pragma unroll
    for (int kt = 0; kt < G1_NT; ++kt) {
        // drain tile kt's 6 loads (oldest); tile kt+1's 6 stay in flight.
        if (kt < G1_NT - 1) asm volatile("s_waitcnt vmcnt(6)" ::: "memory");
        else                asm volatile("s_waitcnt vmcnt(0)" ::: "memory");
        __builtin_amdgcn_s_barrier();   // all waves' stg(kt) landed; slot
                                        // (kt-1)%3's readers are all past.
        const f16* As = S + (kt % 3) * G1_LDSE;
        const f16* Bs = As + G1_BM * 64;
        const bool pf = (kt + 2 < G1_NT);

        f16x8 af0[2][2], af2[2][2], bh0[2][2], bh2[2][2]; // [kk][half-idx]

        // ---- P00: read af01 + bh01 (8), stage 2, MFMA quadrant (i01 x j01)
#pragma unroll
        for (int kk = 0; kk < 2; ++kk) {
            const int fo = (((q + 4 * kk) ^ (m & 7)) << 3);
#pragma unroll
            for (int i = 0; i < 2; ++i) {
                af0[kk][i] = *(const f16x8*)&As[(wr * 64 + i * 16 + m) * 64 + fo];
                bh0[kk][i] = *(const f16x8*)&Bs[(wc * 64 + i * 16 + m) * 64 + fo];
            }
        }
        if (pf) stg2(kt + 2, 0);
        __builtin_amdgcn_s_barrier();
        asm volatile("s_waitcnt lgkmcnt(0)" ::: "memory");
        __builtin_amdgcn_sched_barrier(0);
        __builtin_amdgcn_s_setprio(1);
#pragma unroll
        for (int kk = 0; kk < 2; ++kk)
#pragma unroll
            for (int i = 0; i < 2; ++i)
#pragma unroll
                for (int j = 0; j < 2; ++j)
                    acc[i][j] = __builtin_amdgcn_mfma_f32_16x16x32_f16(
                        af0[kk][i], bh0[kk][j], acc[i][j], 0, 0, 0);
        __builtin_amdgcn_s_setprio(0);

        // ---- P01: read bh23 (4), stage 2, MFMA quadrant (i01 x j23)
#pragma unroll
        for (int kk = 0; kk < 2; ++kk) {
            const int fo = (((q + 4 * kk) ^ (m & 7)) << 3);
#pragma unroll
            for (int j = 0; j < 2; ++j)
                bh2[kk][j] = *(const f16x8*)&Bs[(wc * 64 + (j + 2) * 16 + m) * 64 + fo];
        }
        if (pf) stg2(kt + 2, 2);
        __builtin_amdgcn_s_barrier();
        asm volatile("s_waitcnt lgkmcnt(0)" ::: "memory");
        __builtin_amdgcn_sched_barrier(0);
        __builtin_amdgcn_s_setprio(1);
#pragma unroll
        for (int kk = 0; kk < 2; ++kk)
#pragma unroll
            for (int i = 0; i < 2; ++i)
#pragma unroll
                for (int j = 0; j < 2; ++j)
                    acc[i][j + 2] = __builtin_amdgcn_mfma_f32_16x16x32_f16(
                        af0[kk][i], bh2[kk][j], acc[i][j + 2], 0, 0, 0);
        __builtin_amdgcn_s_setprio(0);

        // ---- P10: read af23 (4), stage 2, MFMA quadrant (i23 x j01)
#pragma unroll
        for (int kk = 0; kk < 2; ++kk) {
            const int fo = (((q + 4 * kk) ^ (m & 7)) << 3);
#pragma unroll
            for (int i = 0; i < 2; ++i)
                af2[kk][i] = *(const f16x8*)&As[(wr * 64 + (i + 2) * 16 + m) * 64 + fo];
        }
        if (pf) stg2(kt + 2, 4);
        __builtin_amdgcn_s_barrier();
        asm volatile("s_waitcnt lgkmcnt(0)" ::: "memory");
        __builtin_amdgcn_sched_barrier(0);
        __builtin_amdgcn_s_setprio(1);
#pragma unroll
        for (int kk = 0; kk < 2; ++kk)
#pragma unroll
            for (int i = 0; i < 2; ++i)
#pragma unroll
                for (int j = 0; j < 2; ++j)
                    acc[i + 2][j] = __builtin_amdgcn_mfma_f32_16x16x32_f16(
                        af2[kk][i], bh0[kk][j], acc[i + 2][j], 0, 0, 0);
        __builtin_amdgcn_s_setprio(0);

        // ---- P11: register-only MFMA quadrant (i23 x j23), no barrier needed
        __builtin_amdgcn_s_setprio(1);
#pragma unroll
        for (int kk = 0; kk < 2; ++kk)
#pragma unroll
            for (int i = 0; i < 2; ++i)
#pragma unroll
                for (int j = 0; j < 2; ++j)
                    acc[i + 2][j + 2] = __builtin_amdgcn_mfma_f32_16x16x32_f16(
                        af2[kk][i], bh2[kk][j], acc[i + 2][j + 2], 0, 0, 0);
        __builtin_amdgcn_s_setprio(0);
    }

    // epilogue: C/D layout col=lane&15, row=q*4+reg
    if (n0 < DINNER) {                     // x_inner cols -> f16 Xb
#pragma unroll
        for (int i = 0; i < 4; i++)
#pragma unroll
            for (int j = 0; j < 4; j++) {
                const int col  = n0 + wc * 64 + j * 16 + m;
                const int rowb = m0 + wr * 64 + i * 16 + q * 4;
#pragma unroll
                for (int r = 0; r < 4; r++)
                    Xb[(size_t)(rowb + r) * DINNER + col] = (f16)acc[i][j][r];
            }
        return;
    }
    if (n0 < 2 * DINNER) {                 // z cols -> f16 Zb
#pragma unroll
        for (int i = 0; i < 4; i++)
#pragma unroll
            for (int j = 0; j < 4; j++) {
                const int col  = n0 - DINNER + wc * 64 + j * 16 + m;
                const int rowb = m0 + wr * 64 + i * 16 + q * 4;
#pragma unroll
                for (int r = 0; r < 4; r++)
                    Zb[(size_t)(rowb + r) * DINNER + col] = (f16)acc[i][j][r];
            }
        return;
    }
#pragma unroll
    for (int i = 0; i < 4; i++)            // B|C|delta -> f32 C at ldc=DXW
#pragma unroll
        for (int j = 0; j < 4; j++) {
            const int col = n0 - 2 * DINNER + wc * 64 + j * 16 + m;
            if (col >= DXW) continue;
            const int rowb = m0 + wr * 64 + i * 16 + q * 4;
#pragma unroll
            for (int r = 0; r < 4; r++)
                C[(size_t)(rowb + r) * DXW + col] = acc[i][j][r];
        }
}

// ---------------------------------------------------------------------------
// GEMM2 (r7 winner): out = Ay[4096,1536](f16) * Bo[768,1536]^T(f16).
//   BM=BN=64, BK=64, 4 waves, ring of 3 x 16KB, counted vmcnt(4), 24 K-tiles.
//   Grid 768 = 3 blocks/CU x 256 CUs: perfect packing.
// ---------------------------------------------------------------------------
#define G2K    1536
#define G2_NT  24            // K-tiles of 64
#define G2_LDSE (128 * 64)   // f16 elems per ring slot (16KB)

__global__ __launch_bounds__(256) void gemm2_pipe(const f16* __restrict__ A,
                                                  const f16* __restrict__ B,
                                                  float* __restrict__ C) {
    __shared__ __align__(16) f16 S[3 * G2_LDSE];   // 48 KB ring

    const int P   = gridDim.x >> 3;                // XCD swizzle: 768 = 8*96
    const int idx = (blockIdx.x & 7) * P + (blockIdx.x >> 3);
    const int m0  = (idx / 12) * 64;               // 64 M-tiles (A-locality slab)
    const int n0  = (idx % 12) * 64;               // 12 N-tiles

    const int tid  = threadIdx.x;
    const int w    = tid >> 6;                     // wave 0..3
    const int lane = tid & 63;
    const int wr   = w >> 1;                       // 0..1 (M)
    const int wc   = w & 1;                        // 0..1 (N)
    const int m    = lane & 15;
    const int q    = lane >> 4;
    const int rl8  = lane >> 3;
    const int bsel = lane & 7;

    // staging map: 16 x 1KB instrs per K-tile; wave w takes t = w + 4*s.
    const f16* gb[4];
#pragma unroll
    for (int s = 0; s < 4; ++s) {
        const int rl  = (w + 4 * s) * 8 + rl8;
        const int blk = bsel ^ (rl & 7);
        gb[s] = (rl < 64) ? A + (size_t)(m0 + rl) * G2K + blk * 8
                          : B + (size_t)(n0 + rl - 64) * G2K + blk * 8;
    }

    f32x4 acc[2][2];
#pragma unroll
    for (int i = 0; i < 2; i++)
#pragma unroll
        for (int j = 0; j < 2; j++) acc[i][j] = (f32x4){0.f, 0.f, 0.f, 0.f};

    auto stg = [&](int kt) {
        f16* dst = S + (kt % 3) * G2_LDSE;
#pragma unroll
        for (int s = 0; s < 4; ++s)
            gld_lds16(dst + (w + 4 * s) * 512, gb[s] + kt * 64);
    };

    stg(0);
    stg(1);

#pragma unroll
    for (int kt = 0; kt < G2_NT; ++kt) {
        // drain tile kt's 4 loads (oldest); tile kt+1's 4 stay in flight.
        if (kt < G2_NT - 1) asm volatile("s_waitcnt vmcnt(4)" ::: "memory");
        else                asm volatile("s_waitcnt vmcnt(0)" ::: "memory");
        __builtin_amdgcn_s_barrier();   // tile kt fully staged; slot (kt-1)%3's
                                        // readers (tile kt-1, pre-barrier) done.
        if (kt + 2 < G2_NT) stg(kt + 2);

        const f16* As = S + (kt % 3) * G2_LDSE;
        const f16* Bs = As + 64 * 64;

        f16x8 af[2][2], bh[2][2];      // [kk][tile]
#pragma unroll
        for (int kk = 0; kk < 2; ++kk) {
            const int fo = (((q + 4 * kk) ^ (m & 7)) << 3);
#pragma unroll
            for (int i = 0; i < 2; ++i) {
                af[kk][i] = *(const f16x8*)&As[(wr * 32 + i * 16 + m) * 64 + fo];
                bh[kk][i] = *(const f16x8*)&Bs[(wc * 32 + i * 16 + m) * 64 + fo];
            }
        }
        asm volatile("s_waitcnt lgkmcnt(0)" ::: "memory");
        __builtin_amdgcn_sched_barrier(0);
        __builtin_amdgcn_s_setprio(1);
#pragma unroll
        for (int kk = 0; kk < 2; ++kk)
#pragma unroll
            for (int i = 0; i < 2; ++i)
#pragma unroll
                for (int j = 0; j < 2; ++j)
                    acc[i][j] = __builtin_amdgcn_mfma_f32_16x16x32_f16(
                        af[kk][i], bh[kk][j], acc[i][j], 0, 0, 0);
        __builtin_amdgcn_s_setprio(0);
    }

    // epilogue: C/D layout col=lane&15, row=q*4+reg
#pragma unroll
    for (int i = 0; i < 2; i++)
#pragma unroll
        for (int j = 0; j < 2; j++) {
            const int col  = n0 + wc * 32 + j * 16 + m;
            const int rowb = m0 + wr * 32 + i * 16 + q * 4;
#pragma unroll
            for (int r = 0; r < 4; r++)
                C[(size_t)(rowb + r) * DIM + col] = acc[i][j][r];
        }
}

// ---------------------------------------------------------------------------
// merged conversions: Ax (f16 x), Bw (f16 W_in, zero-padded), Bo (f16 W_out).
// Packed f16x4 (8B) stores.
// ---------------------------------------------------------------------------
#define E0 (LSEQ * DIM)            // 3,145,728
#define E1 (E0 + NPAD * DIM)       // + 3,637,248
#define E2 (E1 + DIM * DINNER)     // + 1,179,648

__global__ __launch_bounds__(256) void cvt_all(const float* __restrict__ x,
                                               const float* __restrict__ Wi,
                                               const float* __restrict__ Wo,
                                               f16* __restrict__ Ax,
                                               f16* __restrict__ Bw,
                                               f16* __restrict__ Bo) {
    int i = (blockIdx.x * 256 + threadIdx.x) * 4;
    if (i < E0) {
        float4 v = *(const float4*)(x + i);
        f16x4 o = {(f16)v.x, (f16)v.y, (f16)v.z, (f16)v.w};
        *(f16x4*)(Ax + i) = o;
    } else if (i < E1) {
        int e = i - E0;
        int n = e / DIM;
        if (n < NCOLS) {
            float4 v = *(const float4*)(Wi + e);
            f16x4 o = {(f16)v.x, (f16)v.y, (f16)v.z, (f16)v.w};
            *(f16x4*)(Bw + e) = o;
        } else {
            f16x4 o = {(f16)0.f, (f16)0.f, (f16)0.f, (f16)0.f};
            *(f16x4*)(Bw + e) = o;
        }
    } else if (i < E2) {
        int e = i - E1;
        float4 v = *(const float4*)(Wo + e);
        f16x4 o = {(f16)v.x, (f16)v.y, (f16)v.z, (f16)v.w};
        *(f16x4*)(Bo + e) = o;
    }
}

// ---------------------------------------------------------------------------
// scan phase 1 (r10: LDS bulk-staged): conv+silu+softplus fused; local scan
// h=0 -> h_end; store S (rank-1 aprod compression). 2 ch/thread.
// All x/delta loads issued UP FRONT via global_load_lds, waited once; the
// 16-step loop reads only LDS. 52KB -> 3 blocks/CU (12 waves).
// ---------------------------------------------------------------------------
__global__ __launch_bounds__(256, 3) void scan1_kernel(const float* __restrict__ Dxz,
                                                       const f16* __restrict__ Xb,
                                                       const float* __restrict__ Wc,
                                                       const float* __restrict__ A_log,
                                                       float* __restrict__ Sb,
                                                       float* __restrict__ hend) {
    __shared__ __align__(16) f16   Xs[18 * 512];   // rows l0-1 .. l0+16 (18KB)
    __shared__ __align__(16) float Ds[16 * 512];   // delta rows (32KB)
    __shared__ float Bs[CLEN * DSTATE];            // 1KB
    const int tid  = threadIdx.x;
    const int w4   = tid >> 6;
    const int lane = tid & 63;
    const int ch0  = blockIdx.x * 512;             // block channel base
    const int d0   = ch0 + 2 * tid;
    const int c    = blockIdx.y;
    const int l0   = c * CLEN;

    // stage x rows r=0..17 (global row l0-1+r); skip out-of-range rows
    for (int r = w4; r < 18; r += 4) {
        const int gr = l0 - 1 + r;
        if (gr >= 0 && gr < LSEQ)
            gld_lds16(Xs + r * 512, Xb + (size_t)gr * DINNER + ch0 + lane * 8);
    }
    // stage delta rows t=0..15, two 1KB halves each (32 instrs)
    for (int i = w4; i < 32; i += 4) {
        const int t = i >> 1, hh = i & 1;
        gld_lds16(Ds + t * 512 + hh * 256,
                  Dxz + (size_t)(l0 + t) * DXW + 32 + ch0 + hh * 256 + lane * 4);
    }
    for (int i = tid; i < CLEN * DSTATE; i += 256)
        Bs[i] = Dxz[(size_t)(l0 + (i >> 4)) * DXW + (i & 15)];

    float Ar0[DSTATE], Ar1[DSTATE];
#pragma unroll
    for (int n = 0; n < DSTATE; n++) {
        Ar0[n] = -__expf(A_log[d0 * DSTATE + n]);
        Ar1[n] = -__expf(A_log[(d0 + 1) * DSTATE + n]);
    }
    const float w00 = Wc[d0 * 3 + 0], w01 = Wc[d0 * 3 + 1], w02 = Wc[d0 * 3 + 2];
    const float w10 = Wc[d0 * 3 + 3], w11 = Wc[d0 * 3 + 4], w12 = Wc[d0 * 3 + 5];

    asm volatile("s_waitcnt vmcnt(0)" ::: "memory");   // all staging landed
    // zero-fill edge rows that were never staged
    if (l0 == 0)
        *(f16x2*)&Xs[2 * tid] = (f16x2){(f16)0.f, (f16)0.f};
    if (c == NCH - 1)
        *(f16x2*)&Xs[17 * 512 + 2 * tid] = (f16x2){(f16)0.f, (f16)0.f};
    __syncthreads();

    auto ldx = [&](int r) -> float2 {
        f16x2 v = *(const f16x2*)&Xs[r * 512 + 2 * tid];
        return make_float2((float)v.x, (float)v.y);
    };

    float h0[DSTATE], h1[DSTATE];
#pragma unroll
    for (int n = 0; n < DSTATE; n++) { h0[n] = 0.f; h1[n] = 0.f; }
    float S0 = 0.f, S1 = 0.f;

    float2 xm = ldx(0);
    float2 x0 = ldx(1);
    for (int t = 0; t < CLEN; t++) {
        float2 xp = ldx(t + 2);
        float2 dr = *(const float2*)&Ds[t * 512 + 2 * tid];
        float v0  = xm.x * w00 + x0.x * w01 + xp.x * w02;
        float v1  = xm.y * w10 + x0.y * w11 + xp.y * w12;
        float xc0 = __fdividef(v0, 1.f + __expf(-v0));
        float xc1 = __fdividef(v1, 1.f + __expf(-v1));
        float dt0 = (dr.x > 20.f) ? dr.x : __logf(1.f + __expf(dr.x));
        float dt1 = (dr.y > 20.f) ? dr.y : __logf(1.f + __expf(dr.y));
        float u0 = dt0 * xc0, u1 = dt1 * xc1;
        S0 += dt0; S1 += dt1;
#pragma unroll
        for (int n = 0; n < DSTATE; n++) {
            float b = Bs[t * DSTATE + n];
            h0[n] = __expf(dt0 * Ar0[n]) * h0[n] + u0 * b;
            h1[n] = __expf(dt1 * Ar1[n]) * h1[n] + u1 * b;
        }
        xm = x0; x0 = xp;
    }
    *(float2*)&Sb[(size_t)c * DINNER + d0] = make_float2(S0, S1);
#pragma unroll
    for (int n = 0; n < DSTATE; n++)
        *(float2*)&hend[((size_t)c * DSTATE + n) * DINNER + d0] = make_float2(h0[n], h1[n]);
}

// ---------------------------------------------------------------------------
// scan phase 2 (r11: hierarchical affine scan): h' = a*h+e composes as
// (a2,e2)o(a1,e1) = (a2*a1, a2*e1+e2). 16 groups x 16 chunks:
//   (1) thread (elem,group) batch-loads its 16 (s,e) pairs, composes group
//       affine (A,E);
//   (2) 16-thread-per-elem LDS scan over group affines -> group-start h;
//   (3) replay group's 16 chunks from registers, write hinit.
// Serial chain 256 -> 16; grid 96 -> 1536 blocks. Fixed the r10 64us/4%-occ
// scan2. aprod recomputed inline as exp(S*Ar) (rank-1 compression, r8).
// ---------------------------------------------------------------------------
__global__ __launch_bounds__(256) void scan2_kernel(const float* __restrict__ Sb,
                                                    const float* __restrict__ A_log,
                                                    const float* __restrict__ hend,
                                                    float* __restrict__ hinit) {
    __shared__ float As_[16][17];   // [group][elem] (+1 pad)
    __shared__ float Es_[16][17];
    __shared__ float Hs_[16][17];   // group-start h
    const int tid = threadIdx.x;
    const int el  = tid & 15;                 // element within block
    const int grp = tid >> 4;                 // group 0..15
    const int g   = blockIdx.x * 16 + el;     // global element = n*DINNER+d
    const int n   = g / DINNER;
    const int d   = g - n * DINNER;
    const float Ar = -__expf(A_log[d * DSTATE + n]);
    const size_t S = (size_t)DSTATE * DINNER;

    // batch-load this group's 16 (s,e) pairs — 32 independent loads
    float sv[16], ev[16];
#pragma unroll
    for (int k = 0; k < 16; ++k) {
        const int c = grp * 16 + k;
        sv[k] = Sb[(size_t)c * DINNER + d];
        ev[k] = hend[(size_t)c * S + g];
    }
    // compose group affine (A,E); keep a_k for the replay
    float av[16];
    float A = 1.f, E = 0.f;
#pragma unroll
    for (int k = 0; k < 16; ++k) {
        av[k] = __expf(sv[k] * Ar);
        E = av[k] * E + ev[k];
        A = av[k] * A;
    }
    As_[grp][el] = A;
    Es_[grp][el] = E;
    __syncthreads();
    if (tid < 16) {                           // per-elem scan over 16 groups
        float h = 0.f;
#pragma unroll
        for (int gq = 0; gq < 16; ++gq) {
            Hs_[gq][tid] = h;
            h = As_[gq][tid] * h + Es_[gq][tid];
        }
    }
    __syncthreads();
    // replay: hinit for each chunk in this thread's group
    float h = Hs_[grp][el];
#pragma unroll
    for (int k = 0; k < 16; ++k) {
        const int c = grp * 16 + k;
        hinit[(size_t)c * S + g] = h;
        h = av[k] * h + ev[k];
    }
}

// ---------------------------------------------------------------------------
// scan phase 3 (r10: LDS bulk-staged): replay from h_init; z-gate; emit Ay.
// x/delta bulk-staged like scan1 (53KB LDS -> 3 blocks/CU); z kept as
// rolling global prefetch (1 load/step).
// ---------------------------------------------------------------------------
__global__ __launch_bounds__(256, 3) void scan3_kernel(const float* __restrict__ Dxz,
                                                       const f16* __restrict__ Xb,
                                                       const f16* __restrict__ Zb,
                                                       const float* __restrict__ Wc,
                                                       const float* __restrict__ A_log,
                                                       const float* __restrict__ hinit,
                                                       const float* __restrict__ Dp,
                                                       f16* __restrict__ Ay) {
    __shared__ __align__(16) f16   Xs[18 * 512];   // 18KB
    __shared__ __align__(16) float Ds[16 * 512];   // 32KB
    __shared__ float Bs[CLEN * DSTATE];            // 1KB
    __shared__ float Cs[CLEN * DSTATE];            // 1KB
    const int tid  = threadIdx.x;
    const int w4   = tid >> 6;
    const int lane = tid & 63;
    const int ch0  = blockIdx.x * 512;
    const int d0   = ch0 + 2 * tid;
    const int c    = blockIdx.y;
    const int l0   = c * CLEN;

    for (int r = w4; r < 18; r += 4) {
        const int gr = l0 - 1 + r;
        if (gr >= 0 && gr < LSEQ)
            gld_lds16(Xs + r * 512, Xb + (size_t)gr * DINNER + ch0 + lane * 8);
    }
    for (int i = w4; i < 32; i += 4) {
        const int t = i >> 1, hh = i & 1;
        gld_lds16(Ds + t * 512 + hh * 256,
                  Dxz + (size_t)(l0 + t) * DXW + 32 + ch0 + hh * 256 + lane * 4);
    }
    for (int i = tid; i < CLEN * DSTATE; i += 256) {
        size_t roff = (size_t)(l0 + (i >> 4)) * DXW;
        Bs[i] = Dxz[roff + (i & 15)];
        Cs[i] = Dxz[roff + 16 + (i & 15)];
    }

    float Ar0[DSTATE], Ar1[DSTATE];
#pragma unroll
    for (int n = 0; n < DSTATE; n++) {
        Ar0[n] = -__expf(A_log[d0 * DSTATE + n]);
        Ar1[n] = -__expf(A_log[(d0 + 1) * DSTATE + n]);
    }
    float h0[DSTATE], h1[DSTATE];
#pragma unroll
    for (int n = 0; n < DSTATE; n++) {
        float2 hv = *(const float2*)&hinit[((size_t)c * DSTATE + n) * DINNER + d0];
        h0[n] = hv.x; h1[n] = hv.y;
    }
    const float Dv0 = Dp[d0], Dv1 = Dp[d0 + 1];
    const float w00 = Wc[d0 * 3 + 0], w01 = Wc[d0 * 3 + 1], w02 = Wc[d0 * 3 + 2];
    const float w10 = Wc[d0 * 3 + 3], w11 = Wc[d0 * 3 + 4], w12 = Wc[d0 * 3 + 5];

    auto ldz2 = [&](int l) -> float2 {
        f16x2 v = *(const f16x2*)&Zb[(size_t)l * DINNER + d0];
        return make_float2((float)v.x, (float)v.y);
    };
    float2 ld_z = ldz2(l0);

    asm volatile("s_waitcnt vmcnt(0)" ::: "memory");
    if (l0 == 0)
        *(f16x2*)&Xs[2 * tid] = (f16x2){(f16)0.f, (f16)0.f};
    if (c == NCH - 1)
        *(f16x2*)&Xs[17 * 512 + 2 * tid] = (f16x2){(f16)0.f, (f16)0.f};
    __syncthreads();

    auto ldx = [&](int r) -> float2 {
        f16x2 v = *(const f16x2*)&Xs[r * 512 + 2 * tid];
        return make_float2((float)v.x, (float)v.y);
    };

    float2 xm = ldx(0);
    float2 x0 = ldx(1);
    for (int t = 0; t < CLEN; t++) {
        const int l = l0 + t;
        float2 xp = ldx(t + 2);
        float2 dr = *(const float2*)&Ds[t * 512 + 2 * tid];
        float2 zv = ld_z;
        if (t + 1 < CLEN) ld_z = ldz2(l + 1);
        float v0  = xm.x * w00 + x0.x * w01 + xp.x * w02;
        float v1  = xm.y * w10 + x0.y * w11 + xp.y * w12;
        float xc0 = __fdividef(v0, 1.f + __expf(-v0));
        float xc1 = __fdividef(v1, 1.f + __expf(-v1));
        float dt0 = (dr.x > 20.f) ? dr.x : __logf(1.f + __expf(dr.x));
        float dt1 = (dr.y > 20.f) ? dr.y : __logf(1.f + __expf(dr.y));
        float u0 = dt0 * xc0, u1 = dt1 * xc1;
        float y0 = 0.f, y1 = 0.f;
#pragma unroll
        for (int n = 0; n < DSTATE; n++) {
            float b  = Bs[t * DSTATE + n];
            float cc = Cs[t * DSTATE + n];
            h0[n] = __expf(dt0 * Ar0[n]) * h0[n] + u0 * b;
            h1[n] = __expf(dt1 * Ar1[n]) * h1[n] + u1 * b;
            y0 += h0[n] * cc;
            y1 += h1[n] * cc;
        }
        float sz0 = __fdividef(zv.x, 1.f + __expf(-zv.x));
        float sz1 = __fdividef(zv.y, 1.f + __expf(-zv.y));
        f16x2 o = {(f16)((y0 + xc0 * Dv0) * sz0), (f16)((y1 + xc1 * Dv1) * sz1)};
        *(f16x2*)&Ay[(size_t)l * DINNER + d0] = o;
        xm = x0; x0 = xp;
    }
}

// ---------------------------------------------------------------------------
extern "C" void kernel_launch(void* const* d_in, const int* in_sizes, int n_in,
                              void* d_out, int out_size, void* d_ws, size_t ws_size,
                              hipStream_t stream) {
    const float* x     = (const float*)d_in[0];
    const float* W_in  = (const float*)d_in[1];
    const float* W_conv= (const float*)d_in[2];
    const float* W_out = (const float*)d_in[3];
    const float* A_log = (const float*)d_in[4];
    const float* Dp    = (const float*)d_in[5];
    float* out = (float*)d_out;

    // workspace carve-up (~111 MB)
    float* ws  = (float*)d_ws;
    float* Dxz = ws;                                  // 4096*1568 f32
    float* hi  = Dxz + (size_t)LSEQ * DXW;            // hinit: NCH*16*1536
    float* he  = hi + (size_t)NCH * DSTATE * DINNER;  // hend:  NCH*16*1536
    float* Sb  = he + (size_t)NCH * DSTATE * DINNER;  // S:     NCH*1536
    f16* Ax = (f16*)(Sb + (size_t)NCH * DINNER);      // 4096*768
    f16* Ay = Ax + (size_t)LSEQ * DIM;                // 4096*1536
    f16* Bw = Ay + (size_t)LSEQ * DINNER;             // 4736*768
    f16* Bo = Bw + (size_t)NPAD * DIM;                // 768*1536
    f16* Zb = Bo + (size_t)DIM * DINNER;              // 4096*1536
    f16* Xb = Zb + (size_t)LSEQ * DINNER;             // 4096*1536

    // 0) conversions (one kernel, f16x4 packed stores)
    cvt_all<<<E2 / 1024, 256, 0, stream>>>(x, W_in, W_out, Ax, Bw, Bo);

    // 1) xz = x @ W_in^T : 4-phase pipelined 256x128 tiles, counted vmcnt(6).
    //    592 blocks (= 8*74 XCD swizzle), 8Mx37N supertile mapping.
    gemm1_pipe<<<592, 512, 0, stream>>>(Ax, Bw, Dxz, Xb, Zb);

    // 2) chunked scan: NCH=256 chunks of CLEN=16; hierarchical scan2
    scan1_kernel<<<dim3(DINNER / 512, NCH), 256, 0, stream>>>(
        Dxz, Xb, W_conv, A_log, Sb, he);
    scan2_kernel<<<(DINNER * DSTATE) / 16, 256, 0, stream>>>(Sb, A_log, he, hi);
    scan3_kernel<<<dim3(DINNER / 512, NCH), 256, 0, stream>>>(
        Dxz, Xb, Zb, W_conv, A_log, hi, Dp, Ay);

    // 3) out = Ay @ W_out^T : pipelined ring-of-3, counted vmcnt(4), 24 K-tiles.
    //    64 M-tiles x 12 N-tiles = 768 blocks (= 8*96, XCD swizzle, A-locality)
    gemm2_pipe<<<768, 256, 0, stream>>>(Ay, Bo, out);
}